// Round 7
// baseline (128.903 us; speedup 1.0000x reference)
//
#include <hip/hip_runtime.h>
#include <hip/hip_bf16.h>

#define B_DIM 4096
#define D_DIM 768
#define BM 256            // tile is BM x BM
#define BK 64
#define NSTEP (D_DIM / BK)   // 12
#define NTI (B_DIM / BM)     // 16 tiles per dim -> 256 blocks

typedef __bf16 bf16_t;
typedef bf16_t bf16x8 __attribute__((ext_vector_type(8)));
typedef float f32x4 __attribute__((ext_vector_type(4)));

static __device__ __forceinline__ ushort f2bf(float v) {
    __hip_bfloat16 h = __float2bfloat16(v);
    return *reinterpret_cast<const ushort*>(&h);
}

// ---------------- Kernel 1: fp32 -> bf16 + row sum-of-squares ----------------
__global__ __launch_bounds__(256) void prep_kernel(
    const float* __restrict__ E, ushort* __restrict__ Ebf, float* __restrict__ sq)
{
    const int lane = threadIdx.x & 63;
    const int row  = blockIdx.x * 4 + (threadIdx.x >> 6);
    const float4* er = reinterpret_cast<const float4*>(E + (size_t)row * D_DIM);
    ushort4* br = reinterpret_cast<ushort4*>(Ebf + (size_t)row * D_DIM);
    float s = 0.f;
    #pragma unroll
    for (int k = 0; k < 3; ++k) {
        float4 v = er[lane + 64 * k];
        s += v.x * v.x + v.y * v.y + v.z * v.z + v.w * v.w;
        ushort4 o;
        o.x = f2bf(v.x); o.y = f2bf(v.y); o.z = f2bf(v.z); o.w = f2bf(v.w);
        br[lane + 64 * k] = o;
    }
    #pragma unroll
    for (int off = 32; off > 0; off >>= 1) s += __shfl_down(s, off);
    if (lane == 0) sq[row] = s;
}

// ---------------- staging: one quarter (2 gload_lds) of a K-step tile -------
// SQ 0: A rows 0-127, SQ 1: A rows 128-255, SQ 2: B rows 0-127, SQ 3: B 128-255.
// Linear LDS dest (required by global_load_lds); global source col
// pre-swizzled c16 ^ (r&7) (rule #21 pair with the swizzled ds_read).
template<int SQ>
__device__ __forceinline__ void stage_quarter(
    const ushort* __restrict__ Ebf, ushort* Adst, ushort* Bdst,
    int row0, int col0, int kk, int tid)
{
    const ushort* gbase = (SQ < 2) ? (Ebf + (size_t)row0 * D_DIM)
                                   : (Ebf + (size_t)col0 * D_DIM);
    ushort* lbase = (SQ < 2) ? Adst : Bdst;
    const int rbase = (SQ & 1) * 128;
    #pragma unroll
    for (int q = 0; q < 2; ++q) {
        const int idx = q * 512 + tid;
        const int rl  = rbase + (idx >> 3);   // row within 256
        const int c16 = idx & 7;              // 16B chunk within 64-col row
        const int cg  = (c16 ^ (rl & 7)) << 3;
        const ushort* g = gbase + (size_t)rl * D_DIM + kk + cg;
        __builtin_amdgcn_global_load_lds(
            (const __attribute__((address_space(1))) void*)g,
            (__attribute__((address_space(3))) void*)(lbase + rl * 64 + c16 * 8),
            16, 0, 0);
    }
}

// ---------------- one m201-style phase: quadrant (QM,QN) -------------------
// { ds-reads (8 or 12 b128) ; stage 1 quarter ; barrier ; lgkmcnt(0) ;
//   setprio(1) 16 MFMA setprio(0) ; barrier }
// bv (B-frags for QN) persists across the two phases sharing QN.
template<int QM, int QN, bool READB, int SQ>
__device__ __forceinline__ void do_phase(
    const ushort* Acur, const ushort* Bcur,
    const ushort* __restrict__ Ebf, ushort* Adst, ushort* Bdst,
    int row0, int col0, int kpre,
    f32x4 (&acc)[8][4], bf16x8 (&bv)[2][2], int wr, int wc, int lane, int tid)
{
    const int l15 = lane & 15;
    const int kq  = (lane >> 4) * 8;

    if (READB) {
        #pragma unroll
        for (int nn = 0; nn < 2; ++nn)
            #pragma unroll
            for (int k2 = 0; k2 < 2; ++k2) {
                const int rb = wc * 64 + (QN * 2 + nn) * 16 + l15;
                const int c  = (k2 * 32 + kq) ^ ((rb & 7) << 3);
                bv[nn][k2] = *reinterpret_cast<const bf16x8*>(Bcur + rb * 64 + c);
            }
    }
    bf16x8 af[4][2];
    #pragma unroll
    for (int mm = 0; mm < 4; ++mm)
        #pragma unroll
        for (int k2 = 0; k2 < 2; ++k2) {
            const int ra = wr * 128 + (QM * 4 + mm) * 16 + l15;
            const int c  = (k2 * 32 + kq) ^ ((ra & 7) << 3);
            af[mm][k2] = *reinterpret_cast<const bf16x8*>(Acur + ra * 64 + c);
        }

    stage_quarter<SQ>(Ebf, Adst, Bdst, row0, col0, kpre, tid);

    __builtin_amdgcn_sched_barrier(0);
    __builtin_amdgcn_s_barrier();
    asm volatile("s_waitcnt lgkmcnt(0)" ::: "memory");
    __builtin_amdgcn_sched_barrier(0);
    __builtin_amdgcn_s_setprio(1);
    #pragma unroll
    for (int mm = 0; mm < 4; ++mm)
        #pragma unroll
        for (int nn = 0; nn < 2; ++nn)
            #pragma unroll
            for (int k2 = 0; k2 < 2; ++k2)
                acc[QM * 4 + mm][QN * 2 + nn] = __builtin_amdgcn_mfma_f32_16x16x32_bf16(
                    af[mm][k2], bv[nn][k2], acc[QM * 4 + mm][QN * 2 + nn], 0, 0, 0);
    __builtin_amdgcn_s_setprio(0);
    __builtin_amdgcn_sched_barrier(0);
    __builtin_amdgcn_s_barrier();
}

// ---------------- Kernel 2: 256^2 tile, 3-buffer, 4-phase-per-K-tile --------
// 8 waves (2x4), wave tile 128x64, 12 K-tiles. Tile entry: vmcnt(8)+barrier
// (own 8 oldest = this tile's loads; 8 newer may fly — never drained to 0).
// Stage of tile t+2 (spread 1 quarter per phase) targets buf[(t+2)%3], whose
// readers (tile t-1) finished before tile t's entry barrier.
__global__ __launch_bounds__(512, 2) void gram_loss_kernel(
    const ushort* __restrict__ Ebf, const float* __restrict__ sq,
    const float* __restrict__ art, float* __restrict__ out)
{
    extern __shared__ char smem[];
    ushort* Ab = (ushort*)smem;              // 3 x [256][64] ushort = 48 KB
    ushort* Bb = (ushort*)(smem + 49152);    // 3 x [256][64] ushort = 48 KB
    float*  red = (float*)(smem + 98304);    // 8 floats

    const int tid  = threadIdx.x;
    const int lane = tid & 63;
    const int wave = tid >> 6;   // 0..7
    const int wr = wave >> 2;    // 0..1
    const int wc = wave & 3;     // 0..3

    // T1: bijective XCD swizzle (256 blocks % 8 == 0, chunk 32)
    const int swz = (blockIdx.x & 7) * 32 + (blockIdx.x >> 3);
    const int tileR = swz >> 4;
    const int tileC = swz & 15;
    const int row0 = tileR * BM;
    const int col0 = tileC * BM;

    f32x4 acc[8][4] = {};

    // prologue: stage tiles 0 and 1 (16 loads in flight)
    stage_quarter<0>(Ebf, Ab, Bb, row0, col0, 0, tid);
    stage_quarter<1>(Ebf, Ab, Bb, row0, col0, 0, tid);
    stage_quarter<2>(Ebf, Ab, Bb, row0, col0, 0, tid);
    stage_quarter<3>(Ebf, Ab, Bb, row0, col0, 0, tid);
    stage_quarter<0>(Ebf, Ab + 8192, Bb + 8192, row0, col0, BK, tid);
    stage_quarter<1>(Ebf, Ab + 8192, Bb + 8192, row0, col0, BK, tid);
    stage_quarter<2>(Ebf, Ab + 8192, Bb + 8192, row0, col0, BK, tid);
    stage_quarter<3>(Ebf, Ab + 8192, Bb + 8192, row0, col0, BK, tid);

    #pragma unroll 3
    for (int st = 0; st < NSTEP; ++st) {
        const int cur = st % 3;
        const int pre = (st + 2) % 3;
        const int kpre = ((st + 2) % NSTEP) * BK;   // wrapped tail: harmless reload
        const ushort* Acur = Ab + cur * 8192;
        const ushort* Bcur = Bb + cur * 8192;
        ushort* Adst = Ab + pre * 8192;
        ushort* Bdst = Bb + pre * 8192;

        // tile entry: this tile's 8 loads landed in every wave, then sync
        asm volatile("s_waitcnt vmcnt(8)" ::: "memory");
        __builtin_amdgcn_s_barrier();
        __builtin_amdgcn_sched_barrier(0);

        bf16x8 bv[2][2];
        do_phase<0, 0, true,  0>(Acur, Bcur, Ebf, Adst, Bdst, row0, col0, kpre,
                                 acc, bv, wr, wc, lane, tid);
        do_phase<1, 0, false, 1>(Acur, Bcur, Ebf, Adst, Bdst, row0, col0, kpre,
                                 acc, bv, wr, wc, lane, tid);
        do_phase<0, 1, true,  2>(Acur, Bcur, Ebf, Adst, Bdst, row0, col0, kpre,
                                 acc, bv, wr, wc, lane, tid);
        do_phase<1, 1, false, 3>(Acur, Bcur, Ebf, Adst, Bdst, row0, col0, kpre,
                                 acc, bv, wr, wc, lane, tid);
    }

    // Epilogue. C/D layout (HW-verified): col = lane&15, row = (lane>>4)*4 + j.
    // Transposed-art trick: sum_{i!=j}(d2_ij - art_ji)^2 == reference sum
    // (relabel, d2 symmetric) -> per (m,n) one aligned float4 art[gj][gi0..+3].
    float lsum = 0.f;
    const int lr = (lane >> 4) * 4;
    const int lc = lane & 15;
    const int rbase = row0 + wr * 128;
    const int cbase = col0 + wc * 64;

    if (tileR != tileC) {
        #pragma unroll
        for (int m = 0; m < 8; ++m) {
            const int gi0 = rbase + m * 16 + lr;
            const float4 sqv = *reinterpret_cast<const float4*>(sq + gi0);
            const float sqi[4] = { sqv.x, sqv.y, sqv.z, sqv.w };
            #pragma unroll
            for (int n = 0; n < 4; ++n) {
                const int gj = cbase + n * 16 + lc;
                const float sqj = sq[gj];
                const float4 am = *reinterpret_cast<const float4*>(
                    &art[(size_t)gj * B_DIM + gi0]);
                const float amv[4] = { am.x, am.y, am.z, am.w };
                #pragma unroll
                for (int j = 0; j < 4; ++j) {
                    const float d2 = sqi[j] + sqj - 2.0f * acc[m][n][j];
                    const float t = d2 - amv[j];
                    lsum += t * t;
                }
            }
        }
    } else {
        #pragma unroll
        for (int m = 0; m < 8; ++m) {
            const int gi0 = rbase + m * 16 + lr;
            const float4 sqv = *reinterpret_cast<const float4*>(sq + gi0);
            const float sqi[4] = { sqv.x, sqv.y, sqv.z, sqv.w };
            #pragma unroll
            for (int n = 0; n < 4; ++n) {
                const int gj = cbase + n * 16 + lc;
                const float sqj = sq[gj];
                const float4 am = *reinterpret_cast<const float4*>(
                    &art[(size_t)gj * B_DIM + gi0]);
                const float amv[4] = { am.x, am.y, am.z, am.w };
                #pragma unroll
                for (int j = 0; j < 4; ++j) {
                    const int gi = gi0 + j;
                    const float d2 = sqi[j] + sqj - 2.0f * acc[m][n][j];
                    const float t = d2 - amv[j];
                    if (gi != gj) lsum += t * t;
                }
            }
        }
    }

    #pragma unroll
    for (int off = 32; off > 0; off >>= 1) lsum += __shfl_down(lsum, off);
    if (lane == 0) red[wave] = lsum;
    __syncthreads();
    if (tid == 0) {
        float tot = 0.f;
        #pragma unroll
        for (int w = 0; w < 8; ++w) tot += red[w];
        const float inv_pairs = 1.0f / ((float)B_DIM * (float)(B_DIM - 1));
        atomicAdd(out, tot * inv_pairs);
    }
}

// ---------------- launch ----------------
extern "C" void kernel_launch(void* const* d_in, const int* in_sizes, int n_in,
                              void* d_out, int out_size, void* d_ws, size_t ws_size,
                              hipStream_t stream) {
    const float* E   = (const float*)d_in[0];   // [4096, 768] fp32
    const float* art = (const float*)d_in[1];   // [4096, 4096] fp32
    float* out = (float*)d_out;                 // scalar fp32

    ushort* Ebf = (ushort*)d_ws;
    float*  sq  = (float*)((char*)d_ws + (size_t)B_DIM * D_DIM * 2);

    const int lds_bytes = 98304 + 64;
    (void)hipFuncSetAttribute((const void*)gram_loss_kernel,
                              hipFuncAttributeMaxDynamicSharedMemorySize, lds_bytes);

    hipMemsetAsync(d_out, 0, sizeof(float), stream);
    prep_kernel<<<B_DIM / 4, 256, 0, stream>>>(E, Ebf, sq);
    gram_loss_kernel<<<NTI * NTI, 512, lds_bytes, stream>>>(Ebf, sq, art, out);
}